// Round 1
// baseline (117.976 us; speedup 1.0000x reference)
//
#include <hip/hip_runtime.h>

// PropagationOnly_SharedPixel: 12-iteration 3x3 box-sum stencil on a 64x64
// grid, per-pixel scale w[i], tanh(2v) nonlinearity. hiddenWeight input is the
// fixed grid adjacency -> never read (structure hardcoded as the stencil).

#define NS     64            // image side
#define HH     (NS * NS)     // 4096 pixels
#define ITERS  12
#define PITCH  68            // LDS row pitch (floats): 64 data + 4 pad, keeps 16B align, staggers banks
#define ROWS   (NS + 2)      // +2 ghost rows (zeroed)
#define GP     (ROWS * PITCH)
#define PRE    4             // 4-float (16B) zeroed prefix so rowp[-1] at (ghost row 0, c0==0) reads 0
#define BUFSZ  (GP + PRE)

__device__ __forceinline__ float fast_rcp(float x) {
#if __has_builtin(__builtin_amdgcn_rcpf)
  return __builtin_amdgcn_rcpf(x);
#else
  return 1.0f / x;
#endif
}

__global__ __launch_bounds__(512, 1)
void prop_kernel(const float* __restrict__ X,
                 const float* __restrict__ pred,
                 const float* __restrict__ w,
                 const float* __restrict__ a,
                 const float* __restrict__ bias,
                 const float* __restrict__ scalar,
                 float* __restrict__ out)
{
  // Double-buffered padded image: ghost row above/below + zero pad cols, so the
  // 3x3 gather is fully branchless (out-of-image neighbors read zeros).
  __shared__ __align__(16) float pool[2][BUFSZ];

  const int t   = threadIdx.x;        // 0..511
  const int b   = blockIdx.x;         // batch element
  const int r   = t >> 3;             // 0..63 (image row)
  const int c0  = (t & 7) << 3;       // 0,8,...,56 (first of 8 owned columns)
  const int pix = r * NS + c0;

  // Zero both buffers entirely (ghosts + pads must be 0; interior overwritten below).
  {
    float4 z = make_float4(0.f, 0.f, 0.f, 0.f);
    float4* p4 = (float4*)&pool[0][0];
    const int n4 = (2 * BUFSZ) / 4;   // 2246 float4s
    for (int i = t; i < n4; i += 512) p4[i] = z;
  }

  const size_t gb = (size_t)b * HH + pix;
  const float4 x0  = *(const float4*)(X    + gb);
  const float4 x1  = *(const float4*)(X    + gb + 4);
  const float4 p0  = *(const float4*)(pred + gb);
  const float4 p1  = *(const float4*)(pred + gb + 4);
  const float4 w0  = *(const float4*)(w    + pix);
  const float4 w1  = *(const float4*)(w    + pix + 4);
  const float4 a0  = *(const float4*)(a    + pix);
  const float4 a1  = *(const float4*)(a    + pix + 4);
  const float4 bb0 = *(const float4*)(bias + pix);
  const float4 bb1 = *(const float4*)(bias + pix + 4);
  const float  sc  = scalar[0];

  const float pv[8] = {p0.x, p0.y, p0.z, p0.w, p1.x, p1.y, p1.z, p1.w};
  const float xv[8] = {x0.x, x0.y, x0.z, x0.w, x1.x, x1.y, x1.z, x1.w};
  const float av[8] = {a0.x, a0.y, a0.z, a0.w, a1.x, a1.y, a1.z, a1.w};
  const float bv[8] = {bb0.x, bb0.y, bb0.z, bb0.w, bb1.x, bb1.y, bb1.z, bb1.w};
  const float wr[8] = {w0.x, w0.y, w0.z, w0.w, w1.x, w1.y, w1.z, w1.w};

  // Loop-invariant const term: u_fix + bias + a*X  (u_fix clamps exact -1 -> 0)
  float cst[8];
#pragma unroll
  for (int k = 0; k < 8; ++k) {
    const float uf = (pv[k] == -1.0f) ? 0.0f : pv[k];
    cst[k] = uf + bv[k] + av[k] * xv[k];
  }

  __syncthreads();  // zeros visible before interior init store

  float* ua = &pool[0][PRE];
  float* ub = &pool[1][PRE];
  {
    float* dst = ua + (r + 1) * PITCH + c0;   // initial u = pred (raw, NOT u_fix)
    *(float4*)dst       = p0;
    *(float4*)(dst + 4) = p1;
  }
  __syncthreads();

  float un[8];
  for (int it = 0; it < ITERS; ++it) {
    float s[8] = {0.f, 0.f, 0.f, 0.f, 0.f, 0.f, 0.f, 0.f};
#pragma unroll
    for (int dr = 0; dr < 3; ++dr) {
      // ghost coords: reading rows r+dr (dr=0..2) == image rows r-1..r+1
      const float* rowp = ua + (r + dr) * PITCH + c0;
      const float4 m0 = *(const float4*)rowp;
      const float4 m1 = *(const float4*)(rowp + 4);
      const float mL = rowp[-1];   // zero pad at image edge
      const float mR = rowp[8];    // zero pad at image edge
      s[0] += mL   + m0.x + m0.y;
      s[1] += m0.x + m0.y + m0.z;
      s[2] += m0.y + m0.z + m0.w;
      s[3] += m0.z + m0.w + m1.x;
      s[4] += m0.w + m1.x + m1.y;
      s[5] += m1.x + m1.y + m1.z;
      s[6] += m1.y + m1.z + m1.w;
      s[7] += m1.z + m1.w + mR;
    }
#pragma unroll
    for (int k = 0; k < 8; ++k) {
      const float v  = fmaf(wr[k], s[k], cst[k]);
      const float tt = v * sc;
      // tanh(tt) = sign(tt) * (1-e)/(1+e), e = exp(-2|tt|)  (no overflow path)
      const float e  = __expf(-2.0f * fabsf(tt));
      const float th = (1.0f - e) * fast_rcp(1.0f + e);
      un[k] = copysignf(th, tt);
    }
    if (it + 1 < ITERS) {
      float* dst = ub + (r + 1) * PITCH + c0;
      *(float4*)dst       = make_float4(un[0], un[1], un[2], un[3]);
      *(float4*)(dst + 4) = make_float4(un[4], un[5], un[6], un[7]);
      float* tmp = ua; ua = ub; ub = tmp;
      __syncthreads();
    }
  }

  // Final iteration's u goes straight from registers to global.
  float* op = out + gb;
  *(float4*)op       = make_float4(un[0], un[1], un[2], un[3]);
  *(float4*)(op + 4) = make_float4(un[4], un[5], un[6], un[7]);
}

extern "C" void kernel_launch(void* const* d_in, const int* in_sizes, int n_in,
                              void* d_out, int out_size, void* d_ws, size_t ws_size,
                              hipStream_t stream) {
  const float* X    = (const float*)d_in[0];
  const float* pred = (const float*)d_in[1];
  const float* w    = (const float*)d_in[2];
  const float* a    = (const float*)d_in[3];
  const float* bias = (const float*)d_in[4];
  const float* scal = (const float*)d_in[5];
  // d_in[6] = hiddenWeight: fixed 3x3 grid adjacency, hardcoded as the stencil.
  // d_in[7] = dtype: unused.
  float* out = (float*)d_out;
  const int B = in_sizes[0] / HH;   // 128
  prop_kernel<<<B, 512, 0, stream>>>(X, pred, w, a, bias, scal, out);
}

// Round 2
// 108.961 us; speedup vs baseline: 1.0827x; 1.0827x over previous
//
#include <hip/hip_runtime.h>

// PropagationOnly_SharedPixel: 12-iteration 3x3 box-sum stencil on a 64x64
// grid, per-pixel scale w[i], tanh(scalar*v). hiddenWeight input is the fixed
// grid adjacency -> never read (structure hardcoded as the stencil).
//
// This version: separable stencil. LDS holds horizontal row-sums h (not u);
// horizontal neighbors come from DPP row_shr:1/row_shl:1 within 16-lane rows
// (bound_ctrl=1 gives zero at image edges -- exactly the zero-pad semantics).
// Each thread owns a 2x4 pixel patch; its own two h-rows stay in registers,
// so only rows r-1 and r+2 are read from LDS: 2 ds_read_b128 + 2
// ds_write_b128 per thread per iteration. One barrier per iteration,
// double-buffered h.

#define NS     64
#define HH     (NS * NS)
#define ITERS  12
#define HP     64            // h-row pitch in floats (aligned, no col pad needed)
#define HROWS  (NS + 2)      // + zeroed ghost rows top/bottom

#if __has_builtin(__builtin_amdgcn_exp2f)
#define EXP2F(x) __builtin_amdgcn_exp2f(x)
#else
#define EXP2F(x) exp2f(x)
#endif

#if __has_builtin(__builtin_amdgcn_rcpf)
#define RCPF(x) __builtin_amdgcn_rcpf(x)
#else
#define RCPF(x) (1.0f / (x))
#endif

// value from lane-1 within 16-lane DPP row; 0 at row start (image left edge)
__device__ __forceinline__ float dpp_left(float x) {
  return __int_as_float(__builtin_amdgcn_mov_dpp(__float_as_int(x), 0x111, 0xf, 0xf, true));
}
// value from lane+1 within 16-lane DPP row; 0 at row end (image right edge)
__device__ __forceinline__ float dpp_right(float x) {
  return __int_as_float(__builtin_amdgcn_mov_dpp(__float_as_int(x), 0x101, 0xf, 0xf, true));
}

__global__ __launch_bounds__(512, 1)
void prop_kernel(const float* __restrict__ X,
                 const float* __restrict__ pred,
                 const float* __restrict__ w,
                 const float* __restrict__ a,
                 const float* __restrict__ bias,
                 const float* __restrict__ scalar,
                 float* __restrict__ out)
{
  __shared__ __align__(16) float hbuf[2][HROWS * HP];

  const int t  = threadIdx.x;        // 0..511
  const int b  = blockIdx.x;         // batch element
  const int r2 = t >> 4;             // 0..31 row-pair index; 16 threads per image row
  const int c0 = (t & 15) << 2;      // 0,4,...,60
  const int r0 = r2 << 1;            // first of my two rows

  // Zero the 4 ghost rows (2 buffers x top/bottom), 64 threads x one float4.
  if (t < 64) {
    const int buf = t >> 5;
    const int bot = (t >> 4) & 1;
    float4* p = (float4*)(&hbuf[buf][bot ? (HROWS - 1) * HP : 0]);
    p[t & 15] = make_float4(0.f, 0.f, 0.f, 0.f);
  }

  const int    pix = r0 * NS + c0;
  const size_t g0  = (size_t)b * HH + pix;

  const float4 px0 = *(const float4*)(pred + g0);
  const float4 px1 = *(const float4*)(pred + g0 + NS);
  const float4 xx0 = *(const float4*)(X    + g0);
  const float4 xx1 = *(const float4*)(X    + g0 + NS);
  const float4 ww0 = *(const float4*)(w    + pix);
  const float4 ww1 = *(const float4*)(w    + pix + NS);
  const float4 aa0 = *(const float4*)(a    + pix);
  const float4 aa1 = *(const float4*)(a    + pix + NS);
  const float4 bb0 = *(const float4*)(bias + pix);
  const float4 bb1 = *(const float4*)(bias + pix + NS);

  const float sc  = scalar[0];
  const float c2  = -2.885390082f * fabsf(sc);          // -2*log2(e)*|sc|
  const float ssg = (sc < 0.f) ? -1.f : 1.f;

  float un[8] = {px0.x, px0.y, px0.z, px0.w, px1.x, px1.y, px1.z, px1.w};
  const float xv[8] = {xx0.x, xx0.y, xx0.z, xx0.w, xx1.x, xx1.y, xx1.z, xx1.w};
  const float av[8] = {aa0.x, aa0.y, aa0.z, aa0.w, aa1.x, aa1.y, aa1.z, aa1.w};
  const float bv[8] = {bb0.x, bb0.y, bb0.z, bb0.w, bb1.x, bb1.y, bb1.z, bb1.w};
  const float wr[8] = {ww0.x, ww0.y, ww0.z, ww0.w, ww1.x, ww1.y, ww1.z, ww1.w};

  // Loop-invariant: u_fix + bias + a*X   (u_fix clamps exact -1 -> 0; un==pred here)
  float cst[8];
#pragma unroll
  for (int k = 0; k < 8; ++k) {
    const float uf = (un[k] == -1.0f) ? 0.0f : un[k];
    cst[k] = uf + bv[k] + av[k] * xv[k];
  }

  float* hcur = &hbuf[0][HP];   // +HP: index 0 == image row 0; ghost row at -HP
  float* hnxt = &hbuf[1][HP];
  const int myoff = r0 * HP + c0;

  for (int it = 0; it < ITERS; ++it) {
    // Horizontal 3-sum for my two rows; DPP supplies cross-thread edge terms.
    float h[8];
#pragma unroll
    for (int rr = 0; rr < 2; ++rr) {
      const int kb = rr * 4;
      const float hL = dpp_left(un[kb + 3]);
      const float hR = dpp_right(un[kb + 0]);
      h[kb + 0] = hL        + un[kb + 0] + un[kb + 1];
      h[kb + 1] = un[kb + 0] + un[kb + 1] + un[kb + 2];
      h[kb + 2] = un[kb + 1] + un[kb + 2] + un[kb + 3];
      h[kb + 3] = un[kb + 2] + un[kb + 3] + hR;
    }
    *(float4*)(hcur + myoff)      = make_float4(h[0], h[1], h[2], h[3]);
    *(float4*)(hcur + myoff + HP) = make_float4(h[4], h[5], h[6], h[7]);
    __syncthreads();

    // Vertical 3-sum: my own two h-rows are in registers; fetch r0-1, r0+2.
    const float4 mu = *(const float4*)(hcur + myoff - HP);
    const float4 md = *(const float4*)(hcur + myoff + 2 * HP);
    const float sU[4] = {mu.x, mu.y, mu.z, mu.w};
    const float sD[4] = {md.x, md.y, md.z, md.w};

#pragma unroll
    for (int k = 0; k < 4; ++k) {
      const float s0 = sU[k] + h[k] + h[4 + k];
      const float s1 = h[k] + h[4 + k] + sD[k];
      const float v0 = fmaf(wr[k],     s0, cst[k]);
      const float v1 = fmaf(wr[4 + k], s1, cst[4 + k]);
      // tanh(sc*v) = ssg * sign(v) * (1-e)/(1+e), e = 2^(c2*|v|)  (no overflow)
      const float e0 = EXP2F(c2 * fabsf(v0));
      const float e1 = EXP2F(c2 * fabsf(v1));
      const float t0 = (1.f - e0) * RCPF(1.f + e0);
      const float t1 = (1.f - e1) * RCPF(1.f + e1);
      un[k]     = ssg * copysignf(t0, v0);
      un[4 + k] = ssg * copysignf(t1, v1);
    }
    float* tmp = hcur; hcur = hnxt; hnxt = tmp;   // double buffer, 1 barrier/iter
  }

  float* op = out + g0;
  *(float4*)op        = make_float4(un[0], un[1], un[2], un[3]);
  *(float4*)(op + NS) = make_float4(un[4], un[5], un[6], un[7]);
}

extern "C" void kernel_launch(void* const* d_in, const int* in_sizes, int n_in,
                              void* d_out, int out_size, void* d_ws, size_t ws_size,
                              hipStream_t stream) {
  const float* X    = (const float*)d_in[0];
  const float* pred = (const float*)d_in[1];
  const float* w    = (const float*)d_in[2];
  const float* a    = (const float*)d_in[3];
  const float* bias = (const float*)d_in[4];
  const float* scal = (const float*)d_in[5];
  // d_in[6] = hiddenWeight: fixed 3x3 grid adjacency, hardcoded as the stencil.
  // d_in[7] = dtype: unused.
  float* out = (float*)d_out;
  const int B = in_sizes[0] / HH;   // 128
  prop_kernel<<<B, 512, 0, stream>>>(X, pred, w, a, bias, scal, out);
}